// Round 9
// baseline (126.142 us; speedup 1.0000x reference)
//
#include <hip/hip_runtime.h>

#define N_  16384
#define D_  128
#define M1_ 64
#define K_  8
#define LOG2E 1.44269504088896f

typedef short short8 __attribute__((ext_vector_type(8)));
typedef float f32x4  __attribute__((ext_vector_type(4)));
typedef float f32x2  __attribute__((ext_vector_type(2)));

// pack two f32 -> one dword of 2x bf16 (RNE); no builtin on gfx950
__device__ __forceinline__ unsigned cvt_pk_bf16(float lo, float hi) {
    unsigned r;
    asm("v_cvt_pk_bf16_f32 %0, %1, %2" : "=v"(r) : "v"(lo), "v"(hi));
    return r;
}

// ---- prep: unchanged from verified round-2 (gather, coalesced stores) ----
__global__ void prep_all(const float* __restrict__ x,
                         const float* __restrict__ w1p, const float* __restrict__ b1p,
                         const float* __restrict__ w1n, const float* __restrict__ b1n,
                         const float* __restrict__ w2,  const float* __restrict__ b2,
                         const float* __restrict__ w3,
                         ushort* __restrict__ xbf, ushort* __restrict__ wbf,
                         float* __restrict__ bp, float* __restrict__ vv,
                         float* __restrict__ cv) {
    int bx = blockIdx.x;
    if (bx < 1024) {                                   // x cast+swizzle (gather)
        int g    = bx * 256 + threadIdx.x;             // slot id, 8 ushorts each
        int lane = g & 63;
        int ks   = (g >> 6) & 3;
        int n16  = g >> 8;
        int row   = n16 * 16 + (lane & 15);
        int dbase = ks * 32 + (lane >> 4) * 8;
        const float* xp = x + (size_t)row * D_ + dbase;
        float4 a = *(const float4*)xp;
        float4 b = *(const float4*)(xp + 4);
        union { unsigned u[4]; short8 s; } r;
        r.u[0] = cvt_pk_bf16(a.x, a.y);
        r.u[1] = cvt_pk_bf16(a.z, a.w);
        r.u[2] = cvt_pk_bf16(b.x, b.y);
        r.u[3] = cvt_pk_bf16(b.z, b.w);
        *(short8*)&xbf[(size_t)g * 8] = r.s;           // 16 B coalesced store
    } else if (bx < 1536) {                            // W mask+scale+cast+swizzle
        int g    = (bx - 1024) * 256 + threadIdx.x;
        int lane = g & 63;
        int t    = (g >> 6) & 15;                      // t = ks*4+mt
        int j    = g >> 10;
        int ks = t >> 2, mt = t & 3;
        int m     = mt * 16 + (lane & 15);
        int dbase = ks * 32 + (lane >> 4) * 8;
        const float* pp = w1p + ((size_t)(j * M1_ + m)) * D_ + dbase;
        const float* np = w1n + ((size_t)(j * M1_ + m)) * D_ + dbase;
        float4 p0 = *(const float4*)pp;
        float4 p1 = *(const float4*)(pp + 4);
        float4 n0 = *(const float4*)np;
        float4 n1 = *(const float4*)(np + 4);
        float f[8];
        f[0] = (p0.x - n0.x) * LOG2E; f[1] = (p0.y - n0.y) * LOG2E;
        f[2] = (p0.z - n0.z) * LOG2E; f[3] = (p0.w - n0.w) * LOG2E;
        f[4] = (p1.x - n1.x) * LOG2E; f[5] = (p1.y - n1.y) * LOG2E;
        f[6] = (p1.z - n1.z) * LOG2E; f[7] = (p1.w - n1.w) * LOG2E;
        #pragma unroll
        for (int e = 0; e < 8; e++)
            if (dbase + e == j) f[e] = 0.f;
        union { unsigned u[4]; short8 s; } r;
        r.u[0] = cvt_pk_bf16(f[0], f[1]);
        r.u[1] = cvt_pk_bf16(f[2], f[3]);
        r.u[2] = cvt_pk_bf16(f[4], f[5]);
        r.u[3] = cvt_pk_bf16(f[6], f[7]);
        *(short8*)&wbf[(size_t)g * 8] = r.s;           // 16 B coalesced store
    } else {                                           // b/v/c fold (f32)
        int idx = (bx - 1536) * 256 + threadIdx.x;     // idx < D_*M1_
        int j = idx >> 6, m = idx & 63;
        float v = 0.f;
        for (int k = 0; k < K_; k++) v += w3[j * K_ + k] * w2[k * M1_ + m];
        vv[idx] = v;
        bp[idx] = (b1p[idx] - b1n[idx]) * LOG2E;       // log2e-scaled bias (C-init)
        if (m == 0) {
            float c = 0.f;
            for (int k = 0; k < K_; k++) c += w3[j * K_ + k] * b2[k];
            cv[j] = c;
        }
    }
}

// ---- main: r0 structure; ISSUE-CYCLE reduction. Model (r0-r8): SIMD issue
// bandwidth is saturated (VALUBusy+MfmaUtil ~ 90% at every structure; duration
// tracks total issue cycles, invariant to occupancy/ILP). Cuts this round:
// (1) bias as C-in of ks=0 MFMA: deletes 16 v_mov/st (-32 cyc of ~376).
// (2) packed-f32 epilogue (f32x2 -> v_pk_add/mul_f32 + elementwise_fma):
//     full-rate ~136 -> ~90 cyc/st. exp2 (128 cyc/st) is irreducible.
__global__ __launch_bounds__(256) void main_mfma(
    const ushort* __restrict__ xbf, const ushort* __restrict__ wbf,
    const float* __restrict__ bvec, const float* __restrict__ vvec,
    const float* __restrict__ cvec, float* __restrict__ out) {
    const int tid  = threadIdx.x;
    const int wave = tid >> 6, lane = tid & 63;
    const int quad = lane >> 4, col = lane & 15;
    const int j    = blockIdx.y;
    const int nblk = blockIdx.x;                       // fast dim -> XCD = nblk%8

    // W fragments (A operand): one coalesced 16B/lane load each
    short8 wfrag[4][4];                                // [mt][ks]
    const ushort* wg = wbf + (size_t)j * 8192 + lane * 8;
    #pragma unroll
    for (int ks = 0; ks < 4; ks++)
        #pragma unroll
        for (int mt = 0; mt < 4; mt++)
            wfrag[mt][ks] = *(const short8*)&wg[(ks * 4 + mt) * 512];

    // epilogue constants (f32): lane's C-rows are m = mt*16 + quad*4 + r
    f32x4 bias4[4];
    f32x2 vm01[4], vm23[4];
    #pragma unroll
    for (int mt = 0; mt < 4; mt++) {
        bias4[mt] = *(const f32x4*)&bvec[j * M1_ + mt * 16 + quad * 4];
        f32x4 v   = *(const f32x4*)&vvec[j * M1_ + mt * 16 + quad * 4];
        vm01[mt]  = (f32x2){v[0], v[1]};
        vm23[mt]  = (f32x2){v[2], v[3]};
    }
    const float cj = cvec[j];

    // x fragments (B operand): n16 = nblk*32 + wave + st*4
    const ushort* xg = xbf + ((size_t)(nblk * 32 + wave)) * 2048 + lane * 8;
    float* outp = out + (size_t)(nblk * 512 + wave * 16 + col) * D_ + j;

    short8 abuf[2][4];
    #pragma unroll
    for (int ks = 0; ks < 4; ks++)
        abuf[0][ks] = *(const short8*)&xg[ks * 512];

    float pr[8];                                       // per-st partial sums

    #pragma unroll
    for (int st = 0; st < 8; st++) {
        const int cur = st & 1, nxt = cur ^ 1;
        if (st < 7) {                                   // prefetch next subtile
            const ushort* xn = xg + (size_t)(st + 1) * 8192;
            #pragma unroll
            for (int ks = 0; ks < 4; ks++)
                abuf[nxt][ks] = *(const short8*)&xn[ks * 512];
        }

        // MFMA(st); bias enters as C-in of the ks=0 rank (no init movs)
        f32x4 acc[4];
        #pragma unroll
        for (int mt = 0; mt < 4; mt++)
            acc[mt] = __builtin_amdgcn_mfma_f32_16x16x32_bf16(
                          wfrag[mt][0], abuf[cur][0], bias4[mt], 0, 0, 0);
        #pragma unroll
        for (int ks = 1; ks < 4; ks++)
            #pragma unroll
            for (int mt = 0; mt < 4; mt++)
                acc[mt] = __builtin_amdgcn_mfma_f32_16x16x32_bf16(
                              wfrag[mt][ks], abuf[cur][ks], acc[mt], 0, 0, 0);

        // sigma = 1/(1+2^-t): 4-way combined rcp + packed-f32 elementwise ops.
        // rc*t0 = u1*p23/P = 1/u0, etc. Partial sums stay f32x2 (pk_fma chain).
        f32x2 pacc = {0.f, 0.f};
        #pragma unroll
        for (int mt = 0; mt < 4; mt++) {
            float e0 = __builtin_amdgcn_exp2f(-acc[mt][0]);
            float e1 = __builtin_amdgcn_exp2f(-acc[mt][1]);
            float e2 = __builtin_amdgcn_exp2f(-acc[mt][2]);
            float e3 = __builtin_amdgcn_exp2f(-acc[mt][3]);
            f32x2 u01 = {1.f + e0, 1.f + e1};
            f32x2 u23 = {1.f + e2, 1.f + e3};
            float p01 = u01.x * u01.y;
            float p23 = u23.x * u23.y;
            float rc  = __builtin_amdgcn_rcpf(p01 * p23);
            f32x2 t01 = p23 * u01.yx;                  // {p23*u1, p23*u0}
            f32x2 t23 = p01 * u23.yx;                  // {p01*u3, p01*u2}
            f32x2 s   = __builtin_elementwise_fma(t23, vm23[mt], t01 * vm01[mt]);
            pacc = __builtin_elementwise_fma(s, (f32x2){rc, rc}, pacc);
        }
        pr[st] = pacc.x + pacc.y;                       // NO shuffles/stores in loop
    }

    // tail: 16 independent cross-quad shuffles (pipelined), then 8 stores
    #pragma unroll
    for (int st = 0; st < 8; st++)
        pr[st] += __shfl_xor(pr[st], 16);
    #pragma unroll
    for (int st = 0; st < 8; st++)
        pr[st] += __shfl_xor(pr[st], 32);
    if (quad == 0) {
        #pragma unroll
        for (int st = 0; st < 8; st++)
            outp[(size_t)st * 64 * D_] = pr[st] + cj;
    }
}

// ---- fp32 fallback (workspace too small) ----
__global__ void fallback_kernel(const float* __restrict__ x,
                                const float* __restrict__ w1p, const float* __restrict__ b1p,
                                const float* __restrict__ w1n, const float* __restrict__ b1n,
                                const float* __restrict__ w2,  const float* __restrict__ b2,
                                const float* __restrict__ w3,  float* __restrict__ out) {
    int n = blockIdx.x, j = blockIdx.y, m = threadIdx.x;
    const float* xr = x + (size_t)n * D_;
    const float* wp = w1p + ((size_t)j * M1_ + m) * D_;
    const float* wn = w1n + ((size_t)j * M1_ + m) * D_;
    float acc = 0.f;
    for (int d = 0; d < D_; d++) {
        if (d == j) continue;
        acc += xr[d] * (wp[d] - wn[d]);
    }
    acc += b1p[j * M1_ + m] - b1n[j * M1_ + m];
    float h = 1.f / (1.f + __expf(-acc));
    float vmv = 0.f;
    for (int k = 0; k < K_; k++) vmv += w3[j * K_ + k] * w2[k * M1_ + m];
    float p = h * vmv;
    for (int off = 1; off < 64; off <<= 1) p += __shfl_xor(p, off);
    if (m == 0) {
        float c = 0.f;
        for (int k = 0; k < K_; k++) c += w3[j * K_ + k] * b2[k];
        out[(size_t)n * D_ + j] = p + c;
    }
}

extern "C" void kernel_launch(void* const* d_in, const int* in_sizes, int n_in,
                              void* d_out, int out_size, void* d_ws, size_t ws_size,
                              hipStream_t stream) {
    const float* x   = (const float*)d_in[0];
    const float* w1p = (const float*)d_in[1];
    const float* b1p = (const float*)d_in[2];
    const float* w1n = (const float*)d_in[3];
    const float* b1n = (const float*)d_in[4];
    const float* w2  = (const float*)d_in[5];
    const float* b2  = (const float*)d_in[6];
    const float* w3  = (const float*)d_in[7];
    float* out = (float*)d_out;

    const size_t off_x = 0;
    const size_t off_w = off_x + (size_t)N_ * D_ * 2;          // x bf16: 4 MB
    const size_t off_b = off_w + (size_t)D_ * M1_ * D_ * 2;    // W bf16: 2 MB
    const size_t off_v = off_b + (size_t)D_ * M1_ * 4;
    const size_t off_c = off_v + (size_t)D_ * M1_ * 4;
    const size_t need  = off_c + (size_t)D_ * 4;

    if (ws_size < need) {
        fallback_kernel<<<dim3(N_, D_), 64, 0, stream>>>(x, w1p, b1p, w1n, b1n, w2, b2, w3, out);
        return;
    }

    ushort* xbf = (ushort*)((char*)d_ws + off_x);
    ushort* wbf = (ushort*)((char*)d_ws + off_w);
    float*  bp  = (float*)((char*)d_ws + off_b);
    float*  vv  = (float*)((char*)d_ws + off_v);
    float*  cv  = (float*)((char*)d_ws + off_c);

    prep_all<<<1568, 256, 0, stream>>>(x, w1p, b1p, w1n, b1n, w2, b2, w3,
                                       xbf, wbf, bp, vv, cv);
    main_mfma<<<dim3(32, 128), 256, 0, stream>>>(xbf, wbf, bp, vv, cv, out);
}